// Round 10
// baseline (133.077 us; speedup 1.0000x reference)
//
#include <hip/hip_runtime.h>

typedef __attribute__((ext_vector_type(8))) __bf16 bf16x8;
typedef __attribute__((ext_vector_type(4))) float f32x4;

#define MAX_ITER_N 20
#define F_TOL_F 1e-6f
#define FREE_NUM_N 64

#define BSZ 1024
#define IN_DIM 512
#define HID 1024
#define OUT_DIM 256
#define M_CON 128

// workspace layout (float offsets); ctrl region [0..48) zeroed by g1 extra block
#define WS_DONE  0                         // uint: loop completion counter
#define WS_RES   8                         // 32 uints: per-iter residuals
#define WS_BP    48                        // 256 f32: bias_proj
#define WS_H1    304                       // h1 bf16 [1024][1024]
#define WS_H2    (WS_H1 + 524288)          // W1 bf16 FRAGMENT-ORDER [8w][8ct][32ks][64lane][8]
#define WS_W2C   (WS_H2 + 524288)          // W2 bf16 FRAGMENT-ORDER [16cb][32ks][64lane][8]
#define WS_WZG   (WS_W2C + 131072)         // Wz bf16 FRAGMENT-ORDER [16cb][8ks][64lane][8]
#define WS_AG    (WS_WZG + 32768)          // A  bf16 FRAGMENT-ORDER [8mb][8ks][64lane][8]

__device__ __forceinline__ unsigned short f2bf(float f) {
    unsigned int u = __float_as_uint(f);
    u += 0x7fffu + ((u >> 16) & 1u);
    return (unsigned short)(u >> 16);
}

__device__ __forceinline__ unsigned int pk2(float a, float b) {
    return (unsigned int)f2bf(a) | ((unsigned int)f2bf(b) << 16);
}

__device__ __forceinline__ void cvt8(const float* s, unsigned short* d) {
    float4 v0 = *(const float4*)s, v1 = *(const float4*)(s + 4);
    *(uint4*)d = (uint4){pk2(v0.x, v0.y), pk2(v0.z, v0.w), pk2(v1.x, v1.y), pk2(v1.z, v1.w)};
}

__device__ __forceinline__ void gload_lds16(const unsigned short* g, unsigned short* l) {
    __builtin_amdgcn_global_load_lds(
        (const __attribute__((address_space(1))) unsigned int*)(const void*)g,
        (__attribute__((address_space(3))) unsigned int*)(void*)l, 16, 0, 0);
}

// fragment read from a 64x128 bf16 LDS tile with 4-bit XOR granule swizzle
__device__ __forceinline__ bf16x8 frag128(const unsigned short* lds, int row, int gc) {
    int phys = gc ^ (row & 15);
    return __builtin_bit_cast(bf16x8, *(const uint4*)(lds + row * 128 + phys * 8));
}

// ---- g1: 64x64-tile MFMA GEMM (h1 = relu(x @ W0^T + b0)), BK=128, dbuf LDS ----
// Extra blocks (>=256): W2/Wz/Am/W1 -> bf16 in MFMA FRAGMENT ORDER, bias_proj, ctrl-zero.
template<int K, bool AF32, bool RELU>
__global__ __launch_bounds__(256) void gemm_k(
    const void* __restrict__ Ap, const float* __restrict__ Bf,
    const float* __restrict__ bias, unsigned short* __restrict__ C,
    float* __restrict__ ws,
    const float* __restrict__ W2, const float* __restrict__ Wz,
    const float* __restrict__ Am, const float* __restrict__ b_vec,
    const float* __restrict__ WbP, const float* __restrict__ W1f)
{
    constexpr int NCH = K / 128;
    __shared__ __align__(16) unsigned short sA[2][8192];
    __shared__ __align__(16) unsigned short sB[2][8192];

    const int tid = threadIdx.x;

    if constexpr (AF32) {
        if (blockIdx.x >= 256) {            // side work, overlapped with GEMM
            int eb = blockIdx.x - 256;
            unsigned short* W2c = (unsigned short*)(ws + WS_W2C);
            unsigned short* WzG = (unsigned short*)(ws + WS_WZG);
            unsigned short* AG  = (unsigned short*)(ws + WS_AG);
            unsigned short* W1c = (unsigned short*)(ws + WS_H2);
            float* bp = ws + WS_BP;
            if (eb < 64) {                  // W2 -> fragment-order: F in [0,32768)
                int T = eb * 256 + tid;
#pragma unroll
                for (int h = 0; h < 2; ++h) {
                    int F = 2 * T + h;
                    int cb = F >> 11, ksf = (F >> 6) & 31, lf = F & 63;
                    cvt8(W2 + (cb * 16 + (lf & 15)) * HID + ksf * 32 + (lf >> 4) * 8,
                         W2c + F * 8);
                }
            } else if (eb < 80) {           // Wz -> fragment-order: F in [0,8192)
                int T = (eb - 64) * 256 + tid;
#pragma unroll
                for (int h = 0; h < 2; ++h) {
                    int F = 2 * T + h;
                    int cb = F >> 9, ksf = (F >> 6) & 7, lf = F & 63;
                    cvt8(Wz + (cb * 16 + (lf & 15)) * OUT_DIM + ksf * 32 + (lf >> 4) * 8,
                         WzG + F * 8);
                }
            } else if (eb < 88) {           // Am -> fragment-order: F in [0,4096)
                int T = (eb - 80) * 256 + tid;
#pragma unroll
                for (int h = 0; h < 2; ++h) {
                    int F = 2 * T + h;
                    int mb = F >> 9, ksf = (F >> 6) & 7, lf = F & 63;
                    cvt8(Am + (mb * 16 + (lf & 15)) * OUT_DIM + ksf * 32 + (lf >> 4) * 8,
                         AG + F * 8);
                }
            } else if (eb < 96) {           // 8 blocks: bias_proj, coalesced
                if (eb == 88 && tid < 48) ((unsigned int*)ws)[tid] = 0u;
                int j  = (eb - 88) * 32 + (tid >> 3);
                int kg = tid & 7;
                const float* p = WbP + j * M_CON + kg * 16;
                float s = 0.0f;
#pragma unroll
                for (int i = 0; i < 16; ++i) s += p[i] * b_vec[kg * 16 + i];
#pragma unroll
                for (int off = 4; off > 0; off >>= 1) s += __shfl_xor(s, off);
                if (kg == 0) bp[j] = s;
            } else {                        // 256 blocks: W1 -> fragment-order: F in [0,131072)
                int T = (eb - 96) * 256 + tid;
#pragma unroll
                for (int h = 0; h < 2; ++h) {
                    int F = 2 * T + h;
                    int w8 = F >> 14, ct = (F >> 11) & 7, ksf = (F >> 6) & 31, lf = F & 63;
                    cvt8(W1f + (w8 * 128 + ct * 16 + (lf & 15)) * HID + ksf * 32 + (lf >> 4) * 8,
                         W1c + F * 8);
                }
            }
            return;
        }
    }

    const int w = tid >> 6;
    const int lane = tid & 63;
    const int ln = lane & 15;
    const int q  = lane >> 4;
    const int wr = w >> 1;
    const int wc = w & 1;
    const int row0 = (blockIdx.x >> 4) * 64;
    const int col0 = (blockIdx.x & 15) * 64;

    // reg-staging geometry: granule P = tid + 256*i; row=P>>4, gc=P&15
    int grow[4], ggc[4], lof[4];
#pragma unroll
    for (int i = 0; i < 4; ++i) {
        int P = tid + 256 * i;
        grow[i] = P >> 4; ggc[i] = P & 15;
        lof[i] = grow[i] * 128 + (ggc[i] ^ (grow[i] & 15)) * 8;
    }
    const float* Ab_f = (const float*)Ap + row0 * K;
    const float* Bb = Bf + col0 * K;

    float4 ra[8], rb[8];

    // ---- prologue: stage chunk 0 into buffer 0 ----
#pragma unroll
    for (int i = 0; i < 4; ++i) {
        const float* s = Ab_f + grow[i] * K + ggc[i] * 8;
        ra[2*i]   = *(const float4*)s;
        ra[2*i+1] = *(const float4*)(s + 4);
    }
#pragma unroll
    for (int i = 0; i < 4; ++i) {
        const float* s = Bb + grow[i] * K + ggc[i] * 8;
        rb[2*i]   = *(const float4*)s;
        rb[2*i+1] = *(const float4*)(s + 4);
    }
#pragma unroll
    for (int i = 0; i < 4; ++i)
        *(uint4*)(&sA[0][lof[i]]) = (uint4){
            pk2(ra[2*i].x, ra[2*i].y),   pk2(ra[2*i].z, ra[2*i].w),
            pk2(ra[2*i+1].x, ra[2*i+1].y), pk2(ra[2*i+1].z, ra[2*i+1].w)};
#pragma unroll
    for (int i = 0; i < 4; ++i)
        *(uint4*)(&sB[0][lof[i]]) = (uint4){
            pk2(rb[2*i].x, rb[2*i].y),   pk2(rb[2*i].z, rb[2*i].w),
            pk2(rb[2*i+1].x, rb[2*i+1].y), pk2(rb[2*i+1].z, rb[2*i+1].w)};

    f32x4 acc[2][2];
#pragma unroll
    for (int rm = 0; rm < 2; ++rm)
#pragma unroll
        for (int cn = 0; cn < 2; ++cn)
            acc[rm][cn] = (f32x4){0.f, 0.f, 0.f, 0.f};

    for (int c = 0; c < NCH; ++c) {
        __syncthreads();                     // buf[c&1] staging complete
        const int nb = (c + 1) & 1;
        if (c + 1 < NCH) {                   // issue next-chunk loads (hide under MFMA)
            const int koff = (c + 1) * 128;
#pragma unroll
            for (int i = 0; i < 4; ++i) {
                const float* s = Ab_f + grow[i] * K + koff + ggc[i] * 8;
                ra[2*i]   = *(const float4*)s;
                ra[2*i+1] = *(const float4*)(s + 4);
            }
#pragma unroll
            for (int i = 0; i < 4; ++i) {
                const float* s = Bb + grow[i] * K + koff + ggc[i] * 8;
                rb[2*i]   = *(const float4*)s;
                rb[2*i+1] = *(const float4*)(s + 4);
            }
        }
        const unsigned short* Ac = sA[c & 1];
        const unsigned short* Bc = sB[c & 1];
#pragma unroll
        for (int ks = 0; ks < 4; ++ks) {
            bf16x8 af0 = frag128(Ac, wr * 32 + ln,      ks * 4 + q);
            bf16x8 af1 = frag128(Ac, wr * 32 + 16 + ln, ks * 4 + q);
            bf16x8 bf0 = frag128(Bc, wc * 32 + ln,      ks * 4 + q);
            bf16x8 bf1 = frag128(Bc, wc * 32 + 16 + ln, ks * 4 + q);
            acc[0][0] = __builtin_amdgcn_mfma_f32_16x16x32_bf16(af0, bf0, acc[0][0], 0, 0, 0);
            acc[0][1] = __builtin_amdgcn_mfma_f32_16x16x32_bf16(af0, bf1, acc[0][1], 0, 0, 0);
            acc[1][0] = __builtin_amdgcn_mfma_f32_16x16x32_bf16(af1, bf0, acc[1][0], 0, 0, 0);
            acc[1][1] = __builtin_amdgcn_mfma_f32_16x16x32_bf16(af1, bf1, acc[1][1], 0, 0, 0);
        }
        if (c + 1 < NCH) {                   // cvt + write staged regs → buf nb
#pragma unroll
            for (int i = 0; i < 4; ++i)
                *(uint4*)(&sA[nb][lof[i]]) = (uint4){
                    pk2(ra[2*i].x, ra[2*i].y),   pk2(ra[2*i].z, ra[2*i].w),
                    pk2(ra[2*i+1].x, ra[2*i+1].y), pk2(ra[2*i+1].z, ra[2*i+1].w)};
#pragma unroll
            for (int i = 0; i < 4; ++i)
                *(uint4*)(&sB[nb][lof[i]]) = (uint4){
                    pk2(rb[2*i].x, rb[2*i].y),   pk2(rb[2*i].z, rb[2*i].w),
                    pk2(rb[2*i+1].x, rb[2*i+1].y), pk2(rb[2*i+1].z, rb[2*i+1].w)};
        }
    }

#pragma unroll
    for (int cn = 0; cn < 2; ++cn) {
        const int cc = col0 + wc * 32 + cn * 16 + ln;
        const float bv = bias[cc];
#pragma unroll
        for (int rm = 0; rm < 2; ++rm)
#pragma unroll
            for (int i = 0; i < 4; ++i) {
                int r = row0 + wr * 32 + rm * 16 + q * 4 + i;
                float v = acc[rm][cn][i] + bv;
                if (RELU) v = fmaxf(v, 0.0f);
                C[r * HID + cc] = f2bf(v);
            }
    }
}

// ---- K3: h2 slab (frag-order W1) + gemm3 + 20-iter loop + hot-exit; 64 x 512 ----
// All weight reads fragment-ordered => coalesced sequential 1KB streams.
__global__ __launch_bounds__(512, 1) void k3_k(
    const float* __restrict__ b1f, const float* __restrict__ b2v,
    const float* __restrict__ b_vec, const float* __restrict__ Wzf,
    float* __restrict__ out, float* __restrict__ ws)
{
    __shared__ __align__(16) unsigned short hS1[16 * 1024];  // h1 slab (reused as zF)
    __shared__ __align__(16) unsigned short hS2[16 * 1024];  // h2 slab (LDS-only)
    __shared__ __align__(16) unsigned short zS[2][16][264];  // double-buffered z
    __shared__ float redL[MAX_ITER_N * 8];                   // [ri][wave]
    __shared__ float Tsh;
    __shared__ int hotI;

    unsigned int* done = (unsigned int*)ws;
    unsigned int* res  = (unsigned int*)(ws + WS_RES);
    const float* bp = ws + WS_BP;
    const unsigned short* h1c = (const unsigned short*)(ws + WS_H1);
    const unsigned short* W1c = (const unsigned short*)(ws + WS_H2);
    const unsigned short* W2c = (const unsigned short*)(ws + WS_W2C);
    const unsigned short* WzG = (const unsigned short*)(ws + WS_WZG);
    const unsigned short* AG  = (const unsigned short*)(ws + WS_AG);
    float* outz = out + BSZ * OUT_DIM;

    const int tid  = threadIdx.x;
    const int wave = tid >> 6;
    const int lane = tid & 63;
    const int ln   = lane & 15;
    const int q    = lane >> 4;
    const int bid  = blockIdx.x;
    const int r0   = bid * 16;

    // stage h1[r0:r0+16][0:1024] -> hS1 (swizzled): 2048 granules / 8 waves
#pragma unroll
    for (int i = 0; i < 4; ++i) {
        int G = wave * 256 + i * 64 + lane;          // granule (lane-linear dest)
        int row = G >> 7, phys = G & 127;
        int gc = (phys & ~15) | ((phys & 15) ^ (row & 15));
        gload_lds16(h1c + (r0 + row) * HID + gc * 8, &hS1[(wave * 256 + i * 64) * 8]);
    }

    int colg[2];
    colg[0] = wave * 32 + ln;
    colg[1] = wave * 32 + 16 + ln;
    const bool relu0 = (wave * 32) >= FREE_NUM_N;         // wave-uniform
    const bool relu1 = (wave * 32 + 16) >= FREE_NUM_N;

    // register-resident fragments: fragment-order => coalesced sequential loads
    bf16x8 afr[8];
    const int m = wave * 16 + ln;
    const float bvv = b_vec[m];
#pragma unroll
    for (int ks = 0; ks < 8; ++ks)
        afr[ks] = __builtin_bit_cast(bf16x8,
            *(const uint4*)(AG + ((wave * 8 + ks) * 64 + lane) * 8));
    float bpv[2];
    bf16x8 wzfr[2][8];
#pragma unroll
    for (int nt = 0; nt < 2; ++nt) {
        bpv[nt] = bp[colg[nt]];
#pragma unroll
        for (int ks = 0; ks < 8; ++ks)
            wzfr[nt][ks] = __builtin_bit_cast(bf16x8,
                *(const uint4*)(WzG + (((wave * 2 + nt) * 8 + ks) * 64 + lane) * 8));
    }
    float b1t[8];
#pragma unroll
    for (int ct = 0; ct < 8; ++ct) b1t[ct] = b1f[wave * 128 + ct * 16 + ln];
    __syncthreads();   // hS1 ready (barrier drains vmcnt)

    const f32x4 zero4 = {0.f, 0.f, 0.f, 0.f};

    // ---- h2 slab = relu(h1_slab @ W1^T + b1); frag-order W1 streams ----
    {
        f32x4 hacc[8];
#pragma unroll
        for (int ct = 0; ct < 8; ++ct) hacc[ct] = zero4;
#pragma unroll 2
        for (int ks = 0; ks < 32; ++ks) {
            int gci = ks * 4 + q;
            int phys = (gci & ~15) | ((gci & 15) ^ ln);
            bf16x8 af = __builtin_bit_cast(bf16x8, *(const uint4*)&hS1[ln * 1024 + phys * 8]);
#pragma unroll
            for (int ct = 0; ct < 8; ++ct) {
                bf16x8 wf = __builtin_bit_cast(bf16x8,
                    *(const uint4*)(W1c + (((wave * 8 + ct) * 32 + ks) * 64 + lane) * 8));
                hacc[ct] = __builtin_amdgcn_mfma_f32_16x16x32_bf16(af, wf, hacc[ct], 0, 0, 0);
            }
        }
        // write h2 slab into hS2 with the same granule swizzle gemm3 reads
#pragma unroll
        for (int ct = 0; ct < 8; ++ct) {
            const int c = wave * 128 + ct * 16 + ln;
            const int g = c >> 3;
#pragma unroll
            for (int i = 0; i < 4; ++i) {
                float v = fmaxf(hacc[ct][i] + b1t[ct], 0.0f);
                int row = q * 4 + i;
                int pg = (g & ~15) | ((g & 15) ^ (row & 15));
                hS2[row * 1024 + pg * 8 + (c & 7)] = f2bf(v);
            }
        }
    }
    __syncthreads();   // hS2 complete

    // ---- gemm3: acc3 = h2_slab @ W2^T; fragment-order W2 streams ----
    f32x4 a3a[2], a3b[2];
    a3a[0] = zero4; a3a[1] = zero4; a3b[0] = zero4; a3b[1] = zero4;
#pragma unroll 4
    for (int ks = 0; ks < 16; ++ks) {
        int gciA = ks * 4 + q;
        int physA = (gciA & ~15) | ((gciA & 15) ^ ln);
        bf16x8 afA = __builtin_bit_cast(bf16x8, *(const uint4*)&hS2[ln * 1024 + physA * 8]);
        int gciB = (ks + 16) * 4 + q;
        int physB = (gciB & ~15) | ((gciB & 15) ^ ln);
        bf16x8 afB = __builtin_bit_cast(bf16x8, *(const uint4*)&hS2[ln * 1024 + physB * 8]);
#pragma unroll
        for (int nt = 0; nt < 2; ++nt) {
            bf16x8 wfA = __builtin_bit_cast(bf16x8,
                *(const uint4*)(W2c + (((wave * 2 + nt) * 32 + ks) * 64 + lane) * 8));
            bf16x8 wfB = __builtin_bit_cast(bf16x8,
                *(const uint4*)(W2c + (((wave * 2 + nt) * 32 + ks + 16) * 64 + lane) * 8));
            a3a[nt] = __builtin_amdgcn_mfma_f32_16x16x32_bf16(afA, wfA, a3a[nt], 0, 0, 0);
            a3b[nt] = __builtin_amdgcn_mfma_f32_16x16x32_bf16(afB, wfB, a3b[nt], 0, 0, 0);
        }
    }

    // epilogue: write out0 (f32) and seed zS[0] = bf16(out0)
#pragma unroll
    for (int nt = 0; nt < 2; ++nt) {
        float bv = b2v[colg[nt]];
#pragma unroll
        for (int i = 0; i < 4; ++i) {
            float v = a3a[nt][i] + a3b[nt][i] + bv;
            outz[(r0 + q * 4 + i) * OUT_DIM + colg[nt]] = v;
            zS[0][q * 4 + i][colg[nt]] = f2bf(v);
        }
    }
    __syncthreads();   // zS[0] seed complete

    bf16x8 zfr[8];
#pragma unroll
    for (int ks = 0; ks < 8; ++ks)
        zfr[ks] = __builtin_bit_cast(bf16x8, *(const uint4*)&zS[0][ln][ks * 32 + q * 8]);

    int wb = 1;        // buffer to write this iteration

    for (int t = 1; t <= MAX_ITER_N; ++t) {
        f32x4 aA[2], aB[2], r2a, r2b;
        aA[0] = zero4; aA[1] = zero4; aB[0] = zero4; aB[1] = zero4;
        r2a = zero4; r2b = zero4;
#pragma unroll
        for (int ks = 0; ks < 4; ++ks) {
#pragma unroll
            for (int nt = 0; nt < 2; ++nt) {
                aA[nt] = __builtin_amdgcn_mfma_f32_16x16x32_bf16(zfr[ks],     wzfr[nt][ks],     aA[nt], 0, 0, 0);
                aB[nt] = __builtin_amdgcn_mfma_f32_16x16x32_bf16(zfr[ks + 4], wzfr[nt][ks + 4], aB[nt], 0, 0, 0);
            }
            if (t > 1) {
                r2a = __builtin_amdgcn_mfma_f32_16x16x32_bf16(zfr[ks],     afr[ks],     r2a, 0, 0, 0);
                r2b = __builtin_amdgcn_mfma_f32_16x16x32_bf16(zfr[ks + 4], afr[ks + 4], r2b, 0, 0, 0);
            }
        }
        float vals[2][4];
#pragma unroll
        for (int nt = 0; nt < 2; ++nt) {
            const bool rl = nt ? relu1 : relu0;
#pragma unroll
            for (int i = 0; i < 4; ++i) {
                float v = aA[nt][i] + aB[nt][i] + bpv[nt];
                if (rl) v = fmaxf(v, 0.0f);
                vals[nt][i] = v;
            }
        }
        if (t > 1) {   // residual of z_{t-1} -> redL[t-2][wave] (LDS only)
            float lmax = 0.0f;
#pragma unroll
            for (int i = 0; i < 4; ++i)
                lmax = fmaxf(lmax, fabsf(r2a[i] + r2b[i] - bvv));
#pragma unroll
            for (int off = 32; off > 0; off >>= 1)
                lmax = fmaxf(lmax, __shfl_xor(lmax, off));
            if (lane == 0) redL[(t - 2) * 8 + wave] = lmax;
        }
        if (t == MAX_ITER_N) {
#pragma unroll
            for (int nt = 0; nt < 2; ++nt)
#pragma unroll
                for (int i = 0; i < 4; ++i)
                    out[(r0 + q * 4 + i) * OUT_DIM + colg[nt]] = vals[nt][i];
        }
        // write z_t into the other buffer (no WAR: reads of buf wb^1 already done)
#pragma unroll
        for (int nt = 0; nt < 2; ++nt)
#pragma unroll
            for (int i = 0; i < 4; ++i)
                zS[wb][q * 4 + i][colg[nt]] = f2bf(vals[nt][i]);
        __syncthreads();   // single barrier: z_t visible to all waves
#pragma unroll
        for (int ks = 0; ks < 8; ++ks)
            zfr[ks] = __builtin_bit_cast(bf16x8, *(const uint4*)&zS[wb][ln][ks * 32 + q * 8]);
        wb ^= 1;
    }

    {   // final residual of z_20 -> redL[19][wave]
        f32x4 r2a = zero4, r2b = zero4;
#pragma unroll
        for (int ks = 0; ks < 4; ++ks) {
            r2a = __builtin_amdgcn_mfma_f32_16x16x32_bf16(zfr[ks],     afr[ks],     r2a, 0, 0, 0);
            r2b = __builtin_amdgcn_mfma_f32_16x16x32_bf16(zfr[ks + 4], afr[ks + 4], r2b, 0, 0, 0);
        }
        float lmax = 0.0f;
#pragma unroll
        for (int i = 0; i < 4; ++i)
            lmax = fmaxf(lmax, fabsf(r2a[i] + r2b[i] - bvv));
#pragma unroll
        for (int off = 32; off > 0; off >>= 1)
            lmax = fmaxf(lmax, __shfl_xor(lmax, off));
        if (lane == 0) redL[19 * 8 + wave] = lmax;
    }
    __syncthreads();   // all redL complete

    // ---- flush: 20 parallel atomicMax + local-hot test ----
    bool lhot = true;
    if (tid < MAX_ITER_N) {
        float rv = redL[tid * 8];
#pragma unroll
        for (int w2 = 1; w2 < 8; ++w2) rv = fmaxf(rv, redL[tid * 8 + w2]);
        atomicMax(res + tid, __float_as_uint(rv));
        lhot = (rv > F_TOL_F);               // this block's iter-tid residual exceeds tol
    }
    if (tid < 64) {
        unsigned long long mm = __ballot((tid < MAX_ITER_N) && lhot);
        if (tid == 0) hotI = ((mm & 0xFFFFFull) == 0xFFFFFull) ? 1 : 0;
    }
    __syncthreads();   // flush drained; hotI visible

    // contribute completion regardless (a cold block elsewhere may wait on us)
    if (tid == 0) {
        __threadfence();
        atomicAdd(done, 1u);
    }

    if (hotI) {        // local-hot => global res[t] >= local > TOL for all t => T=20
        if (bid == 0 && tid == 0)
            out[2 * BSZ * OUT_DIM] = (float)(MAX_ITER_N + 1);   // curr_iter = 21
        return;        // hot path: no spin, no decide, no res reads
    }

    // ---- cold path: wait for all blocks, decide, fallback ----
    if (tid == 0) {
        while (__hip_atomic_load(done, __ATOMIC_ACQUIRE, __HIP_MEMORY_SCOPE_AGENT) < 64u)
            __builtin_amdgcn_s_sleep(2);
    }
    __syncthreads();   // all 64 blocks' res[] contributions complete

    {
        float rv = 1e30f;
        if (tid < MAX_ITER_N)
            rv = __uint_as_float(__hip_atomic_load(res + tid, __ATOMIC_ACQUIRE, __HIP_MEMORY_SCOPE_AGENT));
        if (tid < 64) {
            unsigned long long mm = __ballot((tid < MAX_ITER_N) && !(rv > F_TOL_F));
            if (tid == 0) Tsh = (float)(mm ? (int)__ffsll(mm) : MAX_ITER_N);
        }
        __syncthreads();
    }
    const int T = (int)Tsh;
    if (bid == 0 && tid == 0)
        out[2 * BSZ * OUT_DIM] = (float)(T + 1);    // curr_iter
    if (T >= MAX_ITER_N) return;

    // ---- cold fp32 fallback for this block's 16 rows (hS1 reused as zF) ----
    {
        float (*zF)[257] = (float(*)[257])hS1;
        const int row = tid >> 4;                   // valid for tid < 256
        const int c0 = (tid & 15) * 16;
        if (tid < 256)
            for (int i = 0; i < 16; ++i)
                zF[row][c0 + i] = outz[(r0 + row) * OUT_DIM + c0 + i];
        __syncthreads();
        const int j = tid;
        const float bj = (tid < 256) ? bp[j] : 0.0f;
        for (int t = 0; t < T; ++t) {
            float acc[16] = {};
            if (tid < 256) {
                for (int k = 0; k < OUT_DIM; ++k) {
                    float wv = Wzf[j * OUT_DIM + k];
#pragma unroll
                    for (int r = 0; r < 16; ++r) acc[r] += zF[r][k] * wv;
                }
            }
            __syncthreads();
            if (tid < 256) {
#pragma unroll
                for (int r = 0; r < 16; ++r) {
                    float v = acc[r] + bj;
                    if (j >= FREE_NUM_N) v = fmaxf(v, 0.0f);
                    zF[r][j] = v;
                }
            }
            __syncthreads();
        }
        if (tid < 256)
            for (int i = 0; i < 16; ++i)
                out[(r0 + row) * OUT_DIM + c0 + i] = zF[row][c0 + i];
    }
}

extern "C" void kernel_launch(void* const* d_in, const int* in_sizes, int n_in,
                              void* d_out, int out_size, void* d_ws, size_t ws_size,
                              hipStream_t stream) {
    const float* b_primal = (const float*)d_in[0];
    const float* W0     = (const float*)d_in[1];
    const float* b0     = (const float*)d_in[2];
    const float* W1     = (const float*)d_in[3];
    const float* b1     = (const float*)d_in[4];
    const float* W2     = (const float*)d_in[5];
    const float* b2     = (const float*)d_in[6];
    const float* Amat   = (const float*)d_in[7];
    const float* b_vec  = (const float*)d_in[8];
    const float* WzProj = (const float*)d_in[9];
    const float* WbProj = (const float*)d_in[10];
    float* out = (float*)d_out;
    float* ws  = (float*)d_ws;

    unsigned short* h1c = (unsigned short*)(ws + WS_H1);

    // g1: h1 = relu(x @ W0^T + b0); 352 side blocks: fragment-order W2/Wz/Am/W1 +
    //     bias_proj + ctrl-zero (overlapped with the GEMM)
    hipLaunchKernelGGL((gemm_k<IN_DIM, true, true>), dim3(608), dim3(256), 0, stream,
                       (const void*)b_primal, W0, b0, h1c, ws,
                       W2, WzProj, Amat, b_vec, WbProj, W1);
    // k3: per-block h2 slab (frag-order W1) + gemm3 + 20-iter loop + hot-exit
    hipLaunchKernelGGL(k3_k, dim3(64), dim3(512), 0, stream,
                       b1, b2, b_vec, WzProj, out, ws);
}

// Round 11
// 124.677 us; speedup vs baseline: 1.0674x; 1.0674x over previous
//
#include <hip/hip_runtime.h>

typedef __attribute__((ext_vector_type(8))) __bf16 bf16x8;
typedef __attribute__((ext_vector_type(4))) float f32x4;

#define MAX_ITER_N 20
#define F_TOL_F 1e-6f
#define FREE_NUM_N 64

#define BSZ 1024
#define IN_DIM 512
#define HID 1024
#define OUT_DIM 256
#define M_CON 128

// workspace layout (float offsets); ctrl region [0..48) zeroed by g1 extra block
#define WS_DONE  0                         // uint: loop completion counter
#define WS_RES   8                         // 32 uints: per-iter residuals
#define WS_BP    48                        // 256 f32: bias_proj
#define WS_H1    304                       // h1 bf16 [1024][1024]
#define WS_H2    (WS_H1 + 524288)          // h2 bf16 [1024][1024]
#define WS_W2C   (WS_H2 + 524288)          // W2 bf16 FRAGMENT-ORDER [16cb][32ks][64lane][8]
#define WS_WZG   (WS_W2C + 131072)         // Wz bf16 FRAGMENT-ORDER [16cb][8ks][64lane][8]
#define WS_AG    (WS_WZG + 32768)          // A  bf16 FRAGMENT-ORDER [8mb][8ks][64lane][8]
#define WS_W1C   (WS_AG + 16384)           // W1 bf16 row-major [1024][1024]

__device__ __forceinline__ unsigned short f2bf(float f) {
    unsigned int u = __float_as_uint(f);
    u += 0x7fffu + ((u >> 16) & 1u);
    return (unsigned short)(u >> 16);
}

__device__ __forceinline__ unsigned int pk2(float a, float b) {
    return (unsigned int)f2bf(a) | ((unsigned int)f2bf(b) << 16);
}

__device__ __forceinline__ void cvt8(const float* s, unsigned short* d) {
    float4 v0 = *(const float4*)s, v1 = *(const float4*)(s + 4);
    *(uint4*)d = (uint4){pk2(v0.x, v0.y), pk2(v0.z, v0.w), pk2(v1.x, v1.y), pk2(v1.z, v1.w)};
}

__device__ __forceinline__ void cvt16(const float* s, unsigned short* d) {
    cvt8(s, d); cvt8(s + 8, d + 8);
}

__device__ __forceinline__ void gload_lds16(const unsigned short* g, unsigned short* l) {
    __builtin_amdgcn_global_load_lds(
        (const __attribute__((address_space(1))) unsigned int*)(const void*)g,
        (__attribute__((address_space(3))) unsigned int*)(void*)l, 16, 0, 0);
}

// fragment read from a 64x128 bf16 LDS tile with 4-bit XOR granule swizzle
__device__ __forceinline__ bf16x8 frag128(const unsigned short* lds, int row, int gc) {
    int phys = gc ^ (row & 15);
    return __builtin_bit_cast(bf16x8, *(const uint4*)(lds + row * 128 + phys * 8));
}

// ---- 64x64-tile MFMA GEMM, BK=128, double-buffered LDS ----
// AF32 (g1): A,B f32 reg-staged + inline cvt; side blocks (>=256) do all
//            weight conversions + bias_proj + ctrl-zero overlapped with GEMM.
// !AF32 (g2): A,B bf16 via global_load_lds (pre-swizzled source) — zero cvt VALU.
template<int K, bool AF32, bool RELU>
__global__ __launch_bounds__(256) void gemm_k(
    const void* __restrict__ Ap, const void* __restrict__ Bp,
    const float* __restrict__ bias, unsigned short* __restrict__ C,
    float* __restrict__ ws,
    const float* __restrict__ W2, const float* __restrict__ Wz,
    const float* __restrict__ Am, const float* __restrict__ b_vec,
    const float* __restrict__ WbP, const float* __restrict__ W1f)
{
    constexpr int NCH = K / 128;
    __shared__ __align__(16) unsigned short sA[2][8192];
    __shared__ __align__(16) unsigned short sB[2][8192];

    const int tid = threadIdx.x;

    if constexpr (AF32) {
        if (blockIdx.x >= 256) {            // side work, overlapped with GEMM
            int eb = blockIdx.x - 256;
            unsigned short* W2c = (unsigned short*)(ws + WS_W2C);
            unsigned short* WzG = (unsigned short*)(ws + WS_WZG);
            unsigned short* AG  = (unsigned short*)(ws + WS_AG);
            unsigned short* W1c = (unsigned short*)(ws + WS_W1C);
            float* bp = ws + WS_BP;
            if (eb < 64) {                  // W2 -> fragment-order: F in [0,32768)
                int T = eb * 256 + tid;
#pragma unroll
                for (int h = 0; h < 2; ++h) {
                    int F = 2 * T + h;
                    int cb = F >> 11, ksf = (F >> 6) & 31, lf = F & 63;
                    cvt8(W2 + (cb * 16 + (lf & 15)) * HID + ksf * 32 + (lf >> 4) * 8,
                         W2c + F * 8);
                }
            } else if (eb < 80) {           // Wz -> fragment-order: F in [0,8192)
                int T = (eb - 64) * 256 + tid;
#pragma unroll
                for (int h = 0; h < 2; ++h) {
                    int F = 2 * T + h;
                    int cb = F >> 9, ksf = (F >> 6) & 7, lf = F & 63;
                    cvt8(Wz + (cb * 16 + (lf & 15)) * OUT_DIM + ksf * 32 + (lf >> 4) * 8,
                         WzG + F * 8);
                }
            } else if (eb < 88) {           // Am -> fragment-order: F in [0,4096)
                int T = (eb - 80) * 256 + tid;
#pragma unroll
                for (int h = 0; h < 2; ++h) {
                    int F = 2 * T + h;
                    int mb = F >> 9, ksf = (F >> 6) & 7, lf = F & 63;
                    cvt8(Am + (mb * 16 + (lf & 15)) * OUT_DIM + ksf * 32 + (lf >> 4) * 8,
                         AG + F * 8);
                }
            } else if (eb < 96) {           // 8 blocks: bias_proj, coalesced
                if (eb == 88 && tid < 48) ((unsigned int*)ws)[tid] = 0u;
                int j  = (eb - 88) * 32 + (tid >> 3);
                int kg = tid & 7;
                const float* p = WbP + j * M_CON + kg * 16;
                float s = 0.0f;
#pragma unroll
                for (int i = 0; i < 16; ++i) s += p[i] * b_vec[kg * 16 + i];
#pragma unroll
                for (int off = 4; off > 0; off >>= 1) s += __shfl_xor(s, off);
                if (kg == 0) bp[j] = s;
            } else {                        // 256 blocks: W1 -> bf16 row-major
                int base = (eb - 96) * 4096 + tid * 16;
                cvt16(W1f + base, W1c + base);
            }
            return;
        }
    }

    const int w = tid >> 6;
    const int lane = tid & 63;
    const int ln = lane & 15;
    const int q  = lane >> 4;
    const int wr = w >> 1;
    const int wc = w & 1;
    const int row0 = (blockIdx.x >> 4) * 64;
    const int col0 = (blockIdx.x & 15) * 64;

    // reg-staging geometry (AF32): granule P = tid + 256*i
    int grow[4], ggc[4], lof[4];
#pragma unroll
    for (int i = 0; i < 4; ++i) {
        int P = tid + 256 * i;
        grow[i] = P >> 4; ggc[i] = P & 15;
        lof[i] = grow[i] * 128 + (ggc[i] ^ (grow[i] & 15)) * 8;
    }
    // gload_lds geometry (!AF32): pre-swizzled source, lane-linear dest
    int soff[4], dbase[4];
    if constexpr (!AF32) {
#pragma unroll
        for (int i = 0; i < 4; ++i) {
            int P = w * 256 + i * 64 + lane;
            int row = P >> 4, pgc = P & 15;
            soff[i]  = row * K + (pgc ^ (row & 15)) * 8;
            dbase[i] = (w * 256 + i * 64) * 8;
        }
    }
    const float* Ab_f = (const float*)Ap + row0 * K;
    const float* Bb_f = (const float*)Bp + col0 * K;
    const unsigned short* Ab_h = (const unsigned short*)Ap + row0 * K;
    const unsigned short* Bb_h = (const unsigned short*)Bp + col0 * K;

    float4 ra[8], rb[8];

    // ---- prologue: stage chunk 0 into buffer 0 ----
    if constexpr (AF32) {
#pragma unroll
        for (int i = 0; i < 4; ++i) {
            const float* s = Ab_f + grow[i] * K + ggc[i] * 8;
            ra[2*i]   = *(const float4*)s;
            ra[2*i+1] = *(const float4*)(s + 4);
        }
#pragma unroll
        for (int i = 0; i < 4; ++i) {
            const float* s = Bb_f + grow[i] * K + ggc[i] * 8;
            rb[2*i]   = *(const float4*)s;
            rb[2*i+1] = *(const float4*)(s + 4);
        }
#pragma unroll
        for (int i = 0; i < 4; ++i)
            *(uint4*)(&sA[0][lof[i]]) = (uint4){
                pk2(ra[2*i].x, ra[2*i].y),   pk2(ra[2*i].z, ra[2*i].w),
                pk2(ra[2*i+1].x, ra[2*i+1].y), pk2(ra[2*i+1].z, ra[2*i+1].w)};
#pragma unroll
        for (int i = 0; i < 4; ++i)
            *(uint4*)(&sB[0][lof[i]]) = (uint4){
                pk2(rb[2*i].x, rb[2*i].y),   pk2(rb[2*i].z, rb[2*i].w),
                pk2(rb[2*i+1].x, rb[2*i+1].y), pk2(rb[2*i+1].z, rb[2*i+1].w)};
    } else {
#pragma unroll
        for (int i = 0; i < 4; ++i) gload_lds16(Ab_h + soff[i], &sA[0][dbase[i]]);
#pragma unroll
        for (int i = 0; i < 4; ++i) gload_lds16(Bb_h + soff[i], &sB[0][dbase[i]]);
    }

    f32x4 acc[2][2];
#pragma unroll
    for (int rm = 0; rm < 2; ++rm)
#pragma unroll
        for (int cn = 0; cn < 2; ++cn)
            acc[rm][cn] = (f32x4){0.f, 0.f, 0.f, 0.f};

    for (int c = 0; c < NCH; ++c) {
        __syncthreads();                     // buf[c&1] staging complete
        const int nb = (c + 1) & 1;
        if (c + 1 < NCH) {                   // issue next-chunk loads (hide under MFMA)
            const int koff = (c + 1) * 128;
            if constexpr (AF32) {
#pragma unroll
                for (int i = 0; i < 4; ++i) {
                    const float* s = Ab_f + grow[i] * K + koff + ggc[i] * 8;
                    ra[2*i]   = *(const float4*)s;
                    ra[2*i+1] = *(const float4*)(s + 4);
                }
#pragma unroll
                for (int i = 0; i < 4; ++i) {
                    const float* s = Bb_f + grow[i] * K + koff + ggc[i] * 8;
                    rb[2*i]   = *(const float4*)s;
                    rb[2*i+1] = *(const float4*)(s + 4);
                }
            } else {
#pragma unroll
                for (int i = 0; i < 4; ++i)
                    gload_lds16(Ab_h + koff + soff[i], &sA[nb][dbase[i]]);
#pragma unroll
                for (int i = 0; i < 4; ++i)
                    gload_lds16(Bb_h + koff + soff[i], &sB[nb][dbase[i]]);
            }
        }
        const unsigned short* Ac = sA[c & 1];
        const unsigned short* Bc = sB[c & 1];
#pragma unroll
        for (int ks = 0; ks < 4; ++ks) {
            bf16x8 af0 = frag128(Ac, wr * 32 + ln,      ks * 4 + q);
            bf16x8 af1 = frag128(Ac, wr * 32 + 16 + ln, ks * 4 + q);
            bf16x8 bf0 = frag128(Bc, wc * 32 + ln,      ks * 4 + q);
            bf16x8 bf1 = frag128(Bc, wc * 32 + 16 + ln, ks * 4 + q);
            acc[0][0] = __builtin_amdgcn_mfma_f32_16x16x32_bf16(af0, bf0, acc[0][0], 0, 0, 0);
            acc[0][1] = __builtin_amdgcn_mfma_f32_16x16x32_bf16(af0, bf1, acc[0][1], 0, 0, 0);
            acc[1][0] = __builtin_amdgcn_mfma_f32_16x16x32_bf16(af1, bf0, acc[1][0], 0, 0, 0);
            acc[1][1] = __builtin_amdgcn_mfma_f32_16x16x32_bf16(af1, bf1, acc[1][1], 0, 0, 0);
        }
        if constexpr (AF32) {
            if (c + 1 < NCH) {               // cvt + write staged regs → buf nb
#pragma unroll
                for (int i = 0; i < 4; ++i)
                    *(uint4*)(&sA[nb][lof[i]]) = (uint4){
                        pk2(ra[2*i].x, ra[2*i].y),   pk2(ra[2*i].z, ra[2*i].w),
                        pk2(ra[2*i+1].x, ra[2*i+1].y), pk2(ra[2*i+1].z, ra[2*i+1].w)};
#pragma unroll
                for (int i = 0; i < 4; ++i)
                    *(uint4*)(&sB[nb][lof[i]]) = (uint4){
                        pk2(rb[2*i].x, rb[2*i].y),   pk2(rb[2*i].z, rb[2*i].w),
                        pk2(rb[2*i+1].x, rb[2*i+1].y), pk2(rb[2*i+1].z, rb[2*i+1].w)};
            }
        }
    }

#pragma unroll
    for (int cn = 0; cn < 2; ++cn) {
        const int cc = col0 + wc * 32 + cn * 16 + ln;
        const float bv = bias[cc];
#pragma unroll
        for (int rm = 0; rm < 2; ++rm)
#pragma unroll
            for (int i = 0; i < 4; ++i) {
                int r = row0 + wr * 32 + rm * 16 + q * 4 + i;
                float v = acc[rm][cn][i] + bv;
                if (RELU) v = fmaxf(v, 0.0f);
                C[r * HID + cc] = f2bf(v);
            }
    }
}

// ---- K3: per-block gemm3 slab + 20-iter loop + hot-exit tail; 64 x 512 ----
// All weight reads fragment-ordered => coalesced sequential 1KB streams.
__global__ __launch_bounds__(512, 1) void k3_k(
    const float* __restrict__ b2v, const float* __restrict__ b_vec,
    const float* __restrict__ Wzf, float* __restrict__ out,
    float* __restrict__ ws)
{
    __shared__ __align__(16) unsigned short hS[16 * 1024];  // swizzled h2 slab (reused as zF)
    __shared__ __align__(16) unsigned short zS[2][16][264]; // double-buffered z
    __shared__ float redL[MAX_ITER_N * 8];                  // [ri][wave]
    __shared__ float Tsh;
    __shared__ int hotI;

    unsigned int* done = (unsigned int*)ws;
    unsigned int* res  = (unsigned int*)(ws + WS_RES);
    const float* bp = ws + WS_BP;
    const unsigned short* h2c = (const unsigned short*)(ws + WS_H2);
    const unsigned short* W2c = (const unsigned short*)(ws + WS_W2C);
    const unsigned short* WzG = (const unsigned short*)(ws + WS_WZG);
    const unsigned short* AG  = (const unsigned short*)(ws + WS_AG);
    float* outz = out + BSZ * OUT_DIM;

    const int tid  = threadIdx.x;
    const int wave = tid >> 6;
    const int lane = tid & 63;
    const int ln   = lane & 15;
    const int q    = lane >> 4;
    const int bid  = blockIdx.x;
    const int r0   = bid * 16;

    // stage h2[r0:r0+16][0:1024] -> hS (swizzled): 2048 granules / 8 waves
#pragma unroll
    for (int i = 0; i < 4; ++i) {
        int G = wave * 256 + i * 64 + lane;          // granule (lane-linear dest)
        int row = G >> 7, phys = G & 127;
        int gc = (phys & ~15) | ((phys & 15) ^ (row & 15));
        gload_lds16(h2c + (r0 + row) * HID + gc * 8, &hS[(wave * 256 + i * 64) * 8]);
    }

    int colg[2];
    colg[0] = wave * 32 + ln;
    colg[1] = wave * 32 + 16 + ln;
    const bool relu0 = (wave * 32) >= FREE_NUM_N;         // wave-uniform
    const bool relu1 = (wave * 32 + 16) >= FREE_NUM_N;

    // register-resident fragments: fragment-order => coalesced sequential loads
    bf16x8 afr[8];
    const int m = wave * 16 + ln;
    const float bvv = b_vec[m];
#pragma unroll
    for (int ks = 0; ks < 8; ++ks)
        afr[ks] = __builtin_bit_cast(bf16x8,
            *(const uint4*)(AG + ((wave * 8 + ks) * 64 + lane) * 8));
    float bpv[2];
    bf16x8 wzfr[2][8];
#pragma unroll
    for (int nt = 0; nt < 2; ++nt) {
        bpv[nt] = bp[colg[nt]];
#pragma unroll
        for (int ks = 0; ks < 8; ++ks)
            wzfr[nt][ks] = __builtin_bit_cast(bf16x8,
                *(const uint4*)(WzG + (((wave * 2 + nt) * 8 + ks) * 64 + lane) * 8));
    }
    __syncthreads();   // hS ready (barrier drains vmcnt)

    const f32x4 zero4 = {0.f, 0.f, 0.f, 0.f};

    // ---- gemm3: acc3 = h2_slab @ W2^T; fragment-order W2 streams ----
    f32x4 a3a[2], a3b[2];
    a3a[0] = zero4; a3a[1] = zero4; a3b[0] = zero4; a3b[1] = zero4;
#pragma unroll 4
    for (int ks = 0; ks < 16; ++ks) {
        int gciA = ks * 4 + q;
        int physA = (gciA & ~15) | ((gciA & 15) ^ ln);
        bf16x8 afA = __builtin_bit_cast(bf16x8, *(const uint4*)&hS[ln * 1024 + physA * 8]);
        int gciB = (ks + 16) * 4 + q;
        int physB = (gciB & ~15) | ((gciB & 15) ^ ln);
        bf16x8 afB = __builtin_bit_cast(bf16x8, *(const uint4*)&hS[ln * 1024 + physB * 8]);
#pragma unroll
        for (int nt = 0; nt < 2; ++nt) {
            bf16x8 wfA = __builtin_bit_cast(bf16x8,
                *(const uint4*)(W2c + (((wave * 2 + nt) * 32 + ks) * 64 + lane) * 8));
            bf16x8 wfB = __builtin_bit_cast(bf16x8,
                *(const uint4*)(W2c + (((wave * 2 + nt) * 32 + ks + 16) * 64 + lane) * 8));
            a3a[nt] = __builtin_amdgcn_mfma_f32_16x16x32_bf16(afA, wfA, a3a[nt], 0, 0, 0);
            a3b[nt] = __builtin_amdgcn_mfma_f32_16x16x32_bf16(afB, wfB, a3b[nt], 0, 0, 0);
        }
    }

    // epilogue: write out0 (f32) and seed zS[0] = bf16(out0)
#pragma unroll
    for (int nt = 0; nt < 2; ++nt) {
        float bv = b2v[colg[nt]];
#pragma unroll
        for (int i = 0; i < 4; ++i) {
            float v = a3a[nt][i] + a3b[nt][i] + bv;
            outz[(r0 + q * 4 + i) * OUT_DIM + colg[nt]] = v;
            zS[0][q * 4 + i][colg[nt]] = f2bf(v);
        }
    }
    __syncthreads();   // zS[0] seed complete

    bf16x8 zfr[8];
#pragma unroll
    for (int ks = 0; ks < 8; ++ks)
        zfr[ks] = __builtin_bit_cast(bf16x8, *(const uint4*)&zS[0][ln][ks * 32 + q * 8]);

    int wb = 1;        // buffer to write this iteration

    for (int t = 1; t <= MAX_ITER_N; ++t) {
        f32x4 aA[2], aB[2], r2a, r2b;
        aA[0] = zero4; aA[1] = zero4; aB[0] = zero4; aB[1] = zero4;
        r2a = zero4; r2b = zero4;
#pragma unroll
        for (int ks = 0; ks < 4; ++ks) {
#pragma unroll
            for (int nt = 0; nt < 2; ++nt) {
                aA[nt] = __builtin_amdgcn_mfma_f32_16x16x32_bf16(zfr[ks],     wzfr[nt][ks],     aA[nt], 0, 0, 0);
                aB[nt] = __builtin_amdgcn_mfma_f32_16x16x32_bf16(zfr[ks + 4], wzfr[nt][ks + 4], aB[nt], 0, 0, 0);
            }
            if (t > 1) {
                r2a = __builtin_amdgcn_mfma_f32_16x16x32_bf16(zfr[ks],     afr[ks],     r2a, 0, 0, 0);
                r2b = __builtin_amdgcn_mfma_f32_16x16x32_bf16(zfr[ks + 4], afr[ks + 4], r2b, 0, 0, 0);
            }
        }
        float vals[2][4];
#pragma unroll
        for (int nt = 0; nt < 2; ++nt) {
            const bool rl = nt ? relu1 : relu0;
#pragma unroll
            for (int i = 0; i < 4; ++i) {
                float v = aA[nt][i] + aB[nt][i] + bpv[nt];
                if (rl) v = fmaxf(v, 0.0f);
                vals[nt][i] = v;
            }
        }
        if (t > 1) {   // residual of z_{t-1} -> redL[t-2][wave] (LDS only)
            float lmax = 0.0f;
#pragma unroll
            for (int i = 0; i < 4; ++i)
                lmax = fmaxf(lmax, fabsf(r2a[i] + r2b[i] - bvv));
#pragma unroll
            for (int off = 32; off > 0; off >>= 1)
                lmax = fmaxf(lmax, __shfl_xor(lmax, off));
            if (lane == 0) redL[(t - 2) * 8 + wave] = lmax;
        }
        if (t == MAX_ITER_N) {
#pragma unroll
            for (int nt = 0; nt < 2; ++nt)
#pragma unroll
                for (int i = 0; i < 4; ++i)
                    out[(r0 + q * 4 + i) * OUT_DIM + colg[nt]] = vals[nt][i];
        }
        // write z_t into the other buffer (no WAR: reads of buf wb^1 already done)
#pragma unroll
        for (int nt = 0; nt < 2; ++nt)
#pragma unroll
            for (int i = 0; i < 4; ++i)
                zS[wb][q * 4 + i][colg[nt]] = f2bf(vals[nt][i]);
        __syncthreads();   // single barrier: z_t visible to all waves
#pragma unroll
        for (int ks = 0; ks < 8; ++ks)
            zfr[ks] = __builtin_bit_cast(bf16x8, *(const uint4*)&zS[wb][ln][ks * 32 + q * 8]);
        wb ^= 1;
    }

    {   // final residual of z_20 -> redL[19][wave]
        f32x4 r2a = zero4, r2b = zero4;
#pragma unroll
        for (int ks = 0; ks < 4; ++ks) {
            r2a = __builtin_amdgcn_mfma_f32_16x16x32_bf16(zfr[ks],     afr[ks],     r2a, 0, 0, 0);
            r2b = __builtin_amdgcn_mfma_f32_16x16x32_bf16(zfr[ks + 4], afr[ks + 4], r2b, 0, 0, 0);
        }
        float lmax = 0.0f;
#pragma unroll
        for (int i = 0; i < 4; ++i)
            lmax = fmaxf(lmax, fabsf(r2a[i] + r2b[i] - bvv));
#pragma unroll
        for (int off = 32; off > 0; off >>= 1)
            lmax = fmaxf(lmax, __shfl_xor(lmax, off));
        if (lane == 0) redL[19 * 8 + wave] = lmax;
    }
    __syncthreads();   // all redL complete

    // ---- flush: 20 parallel atomicMax + local-hot test ----
    bool lhot = true;
    if (tid < MAX_ITER_N) {
        float rv = redL[tid * 8];
#pragma unroll
        for (int w2 = 1; w2 < 8; ++w2) rv = fmaxf(rv, redL[tid * 8 + w2]);
        atomicMax(res + tid, __float_as_uint(rv));
        lhot = (rv > F_TOL_F);               // this block's iter-tid residual exceeds tol
    }
    if (tid < 64) {
        unsigned long long mm = __ballot((tid < MAX_ITER_N) && lhot);
        if (tid == 0) hotI = ((mm & 0xFFFFFull) == 0xFFFFFull) ? 1 : 0;
    }
    __syncthreads();   // flush drained; hotI visible

    // contribute completion regardless (a cold block elsewhere may wait on us)
    if (tid == 0) {
        __threadfence();
        atomicAdd(done, 1u);
    }

    if (hotI) {        // local-hot => global res[t] >= local > TOL for all t => T=20
        if (bid == 0 && tid == 0)
            out[2 * BSZ * OUT_DIM] = (float)(MAX_ITER_N + 1);   // curr_iter = 21
        return;        // hot path: no spin, no decide, no res reads
    }

    // ---- cold path: wait for all blocks, decide, fallback ----
    if (tid == 0) {
        while (__hip_atomic_load(done, __ATOMIC_ACQUIRE, __HIP_MEMORY_SCOPE_AGENT) < 64u)
            __builtin_amdgcn_s_sleep(2);
    }
    __syncthreads();   // all 64 blocks' res[] contributions complete

    {
        float rv = 1e30f;
        if (tid < MAX_ITER_N)
            rv = __uint_as_float(__hip_atomic_load(res + tid, __ATOMIC_ACQUIRE, __HIP_MEMORY_SCOPE_AGENT));
        if (tid < 64) {
            unsigned long long mm = __ballot((tid < MAX_ITER_N) && !(rv > F_TOL_F));
            if (tid == 0) Tsh = (float)(mm ? (int)__ffsll(mm) : MAX_ITER_N);
        }
        __syncthreads();
    }
    const int T = (int)Tsh;
    if (bid == 0 && tid == 0)
        out[2 * BSZ * OUT_DIM] = (float)(T + 1);    // curr_iter
    if (T >= MAX_ITER_N) return;

    // ---- cold fp32 fallback for this block's 16 rows (hS reused as zF) ----
    {
        float (*zF)[257] = (float(*)[257])hS;
        const int row = tid >> 4;                   // valid for tid < 256
        const int c0 = (tid & 15) * 16;
        if (tid < 256)
            for (int i = 0; i < 16; ++i)
                zF[row][c0 + i] = outz[(r0 + row) * OUT_DIM + c0 + i];
        __syncthreads();
        const int j = tid;
        const float bj = (tid < 256) ? bp[j] : 0.0f;
        for (int t = 0; t < T; ++t) {
            float acc[16] = {};
            if (tid < 256) {
                for (int k = 0; k < OUT_DIM; ++k) {
                    float wv = Wzf[j * OUT_DIM + k];
#pragma unroll
                    for (int r = 0; r < 16; ++r) acc[r] += zF[r][k] * wv;
                }
            }
            __syncthreads();
            if (tid < 256) {
#pragma unroll
                for (int r = 0; r < 16; ++r) {
                    float v = acc[r] + bj;
                    if (j >= FREE_NUM_N) v = fmaxf(v, 0.0f);
                    zF[r][j] = v;
                }
            }
            __syncthreads();
        }
        if (tid < 256)
            for (int i = 0; i < 16; ++i)
                out[(r0 + row) * OUT_DIM + c0 + i] = zF[row][c0 + i];
    }
}

extern "C" void kernel_launch(void* const* d_in, const int* in_sizes, int n_in,
                              void* d_out, int out_size, void* d_ws, size_t ws_size,
                              hipStream_t stream) {
    const float* b_primal = (const float*)d_in[0];
    const float* W0     = (const float*)d_in[1];
    const float* b0     = (const float*)d_in[2];
    const float* W1     = (const float*)d_in[3];
    const float* b1     = (const float*)d_in[4];
    const float* W2     = (const float*)d_in[5];
    const float* b2     = (const float*)d_in[6];
    const float* Amat   = (const float*)d_in[7];
    const float* b_vec  = (const float*)d_in[8];
    const float* WzProj = (const float*)d_in[9];
    const float* WbProj = (const float*)d_in[10];
    float* out = (float*)d_out;
    float* ws  = (float*)d_ws;

    unsigned short* h1c = (unsigned short*)(ws + WS_H1);
    unsigned short* h2c = (unsigned short*)(ws + WS_H2);
    unsigned short* W1c = (unsigned short*)(ws + WS_W1C);

    // g1: h1 = relu(x @ W0^T + b0); 352 side blocks: frag-order W2/Wz/Am +
    //     row-major bf16 W1 + bias_proj + ctrl-zero (overlapped with GEMM)
    hipLaunchKernelGGL((gemm_k<IN_DIM, true, true>), dim3(608), dim3(256), 0, stream,
                       (const void*)b_primal, (const void*)W0, b0, h1c, ws,
                       W2, WzProj, Amat, b_vec, WbProj, W1);
    // g2: h2 = relu(h1 @ W1^T + b1) — both operands bf16 via global_load_lds
    hipLaunchKernelGGL((gemm_k<HID, false, true>), dim3(256), dim3(256), 0, stream,
                       (const void*)h1c, (const void*)W1c, b1, h2c, ws,
                       nullptr, nullptr, nullptr, nullptr, nullptr, nullptr);
    // k3: per-block gemm3 slab (frag-order weights) + 20-iter loop + hot-exit
    hipLaunchKernelGGL(k3_k, dim3(64), dim3(512), 0, stream,
                       b2, b_vec, WzProj, out, ws);
}